// Round 10
// baseline (318.345 us; speedup 1.0000x reference)
//
#include <hip/hip_runtime.h>
#include <math.h>

// MeanShift: x (2,3,96,96) fp32, 5 iters of all-pairs Gaussian-weighted mean.
// SINGLE fused kernel. R8's proven hot loop + math verbatim. Iteration
// exchange via atomicAdd into pre-zeroed acc[t] (R8-proven), synchronized by
// PER-GROUP barriers: the 16 k-blocks of one (b,nt) n-range sync among
// themselves only (block (k,nt) at iter t+1 reads only its own group's
// combined partials). No grid-wide sync exists anywhere.
//
// Deadlock safety: grid 1152 = 4.5 blocks/CU; __launch_bounds__(256,5)
// forces VGPR<=102 -> 5 waves/SIMD -> >=5 blocks/CU capacity (LDS 5x16KB=80
// <=160KB). R9 hung with unbounded VGPR (needed 5 blocks/CU, bound absent).
// Spin uses device-scope RMW (atomicAdd(ctr,0)) -- coherent at the LLC,
// immune to cross-XCD L2 staleness (R9's plain acquire load was suspect #2).
//
// Math: scaled space s = sqrt(50*log2e); w = exp2(2p.y - |p|^2 - |y|^2).
// LDS stages (2px,2py,2pz,-|p|^2); ypar stores PLAIN y (storing 2y was the
// rounds-5/6 NaN bug).

typedef float v2f __attribute__((ext_vector_type(2)));

#define NPTS   9216            // 96*96
#define NB     2
#define TOT    (NB * NPTS)     // 18432
#define MSPLIT 16              // m-slices per n-tile == blocks per group
#define SLICE  (NPTS / MSPLIT) // 576 m per block
#define WSLICE (SLICE / 4)     // 144 m per wave
#define NPB    256             // n per block (4 per thread)
#define NTILES (NPTS / NPB)    // 36
#define NGRP   (NB * NTILES)   // 72 groups of MSPLIT blocks
#define GRIDSZ (NGRP * MSPLIT) // 1152 blocks = 4.5/CU
#define LOG2E  1.44269504088896340736f

__device__ __forceinline__ v2f splat2(float v) { return (v2f){v, v}; }

// acc[t][gid] = float4(num,den), t=0..4, pre-zeroed, atomic-combined.
// bars[grp*16]: per-group arrival counters (64B-padded), pre-zeroed.

__device__ __forceinline__ void group_barrier(int* ctr, int target) {
    __syncthreads();                         // all waves done with prior phase
    if (threadIdx.x == 0) {
        __threadfence();                     // release our atomics/writes
        atomicAdd(ctr, 1);
        while (atomicAdd(ctr, 0) < target)   // device-scope RMW: coherent
            __builtin_amdgcn_s_sleep(2);
        __threadfence();                     // acquire peers' writes
    }
    __syncthreads();
}

__global__ __launch_bounds__(256, 5) void ms_all(const float* __restrict__ x,
                                                 float4* __restrict__ acc,
                                                 int* __restrict__ bars,
                                                 float* __restrict__ out,
                                                 float s) {
    __shared__ float smem[4096];            // 16 KB
    float* const xs = smem;                 // [SLICE] 2*px
    float* const ys = xs + SLICE;           // 2*py
    float* const zs = ys + SLICE;           // 2*pz
    float* const ws = zs + SLICE;           // -|p|^2   (ends at 2304 floats)
    float4* const ypar = (float4*)(smem + 4 * SLICE);  // [NPB] (ends 3328)
    float4* const red  = (float4*)smem;     // [4][NPB] overlay = 4096 floats

    const int tid  = threadIdx.x;
    const int lane = tid & 63;
    const int wv   = tid >> 6;
    const int k    = blockIdx.x % MSPLIT;
    const int grp  = blockIdx.x / MSPLIT;   // == b*NTILES + nt
    const int b    = grp / NTILES;
    const int nt   = grp - b * NTILES;
    const int nbase = nt * NPB;
    const float* xb = x + b * 3 * NPTS;
    const int mbeg = k * SLICE;
    int* const ctr = bars + grp * 16;       // 64B-padded counter

    for (int it = 0; it < 5; ++it) {
        // SoA staging, scaled, 2x folded into coords (x stays L2-hot).
        for (int i = tid; i < SLICE; i += 256) {
            int g = mbeg + i;
            float px = xb[g] * s;
            float py = xb[NPTS + g] * s;
            float pz = xb[2 * NPTS + g] * s;
            xs[i] = 2.f * px;
            ys[i] = 2.f * py;
            zs[i] = 2.f * pz;
            ws[i] = -fmaf(px, px, fmaf(py, py, pz * pz));
        }
        // y for this iteration (scaled). PLAIN y (2x lives in LDS).
        {
            float y0, y1, y2;
            if (it == 0) {
                int n = nbase + tid;
                y0 = xb[n] * s; y1 = xb[NPTS + n] * s; y2 = xb[2 * NPTS + n] * s;
            } else {
                float4 a = acc[(size_t)(it - 1) * TOT + b * NPTS + nbase + tid];
                float inv = 1.0f / a.w;
                y0 = a.x * inv; y1 = a.y * inv; y2 = a.z * inv;
            }
            ypar[tid] = make_float4(y0, y1, y2,
                                    -fmaf(y0, y0, fmaf(y1, y1, y2 * y2)));
        }
        __syncthreads();

        v2f Yx[4], Yy[4], Yz[4], Yw[4], Ax[4], Ay[4], Az[4], Aw[4];
#pragma unroll
        for (int j = 0; j < 4; ++j) {
            float4 yp = ypar[lane + 64 * j];
            Yx[j] = splat2(yp.x); Yy[j] = splat2(yp.y);
            Yz[j] = splat2(yp.z); Yw[j] = splat2(yp.w);
            Ax[j] = splat2(0.f); Ay[j] = splat2(0.f);
            Az[j] = splat2(0.f); Aw[j] = splat2(0.f);
        }

        const float* xsw = xs + wv * WSLICE;
        const float* ysw = ys + wv * WSLICE;
        const float* zsw = zs + wv * WSLICE;
        const float* wsw = ws + wv * WSLICE;

        // R8 hot loop verbatim (prefetch next superiter's 4 LDS float4s).
        float4 PX = *(const float4*)(xsw);
        float4 PY = *(const float4*)(ysw);
        float4 PZ = *(const float4*)(zsw);
        float4 PW = *(const float4*)(wsw);
        for (int i = 0; i < WSLICE; i += 4) {
            float4 NX = *(const float4*)(xsw + i + 4);
            float4 NY = *(const float4*)(ysw + i + 4);
            float4 NZ = *(const float4*)(zsw + i + 4);
            float4 NW = *(const float4*)(wsw + i + 4);
            v2f px0 = (v2f){PX.x, PX.y}, px1 = (v2f){PX.z, PX.w};
            v2f py0 = (v2f){PY.x, PY.y}, py1 = (v2f){PY.z, PY.w};
            v2f pz0 = (v2f){PZ.x, PZ.y}, pz1 = (v2f){PZ.z, PZ.w};
            v2f pw0 = (v2f){PW.x, PW.y}, pw1 = (v2f){PW.z, PW.w};
#pragma unroll
            for (int j = 0; j < 4; ++j) {
                v2f t0 = pw0 + Yw[j];
                t0 = __builtin_elementwise_fma(pz0, Yz[j], t0);
                t0 = __builtin_elementwise_fma(py0, Yy[j], t0);
                t0 = __builtin_elementwise_fma(px0, Yx[j], t0);
                v2f t1 = pw1 + Yw[j];
                t1 = __builtin_elementwise_fma(pz1, Yz[j], t1);
                t1 = __builtin_elementwise_fma(py1, Yy[j], t1);
                t1 = __builtin_elementwise_fma(px1, Yx[j], t1);
                v2f w0, w1;
                w0.x = __builtin_amdgcn_exp2f(t0.x);
                w0.y = __builtin_amdgcn_exp2f(t0.y);
                w1.x = __builtin_amdgcn_exp2f(t1.x);
                w1.y = __builtin_amdgcn_exp2f(t1.y);
                Ax[j] = __builtin_elementwise_fma(w0, px0, Ax[j]);
                Ay[j] = __builtin_elementwise_fma(w0, py0, Ay[j]);
                Az[j] = __builtin_elementwise_fma(w0, pz0, Az[j]);
                Aw[j] += w0;
                Ax[j] = __builtin_elementwise_fma(w1, px1, Ax[j]);
                Ay[j] = __builtin_elementwise_fma(w1, py1, Ay[j]);
                Az[j] = __builtin_elementwise_fma(w1, pz1, Az[j]);
                Aw[j] += w1;
            }
            PX = NX; PY = NY; PZ = NZ; PW = NW;
        }

        // Cross-wave reduction (red overlays staging+ypar; both dead now).
        __syncthreads();
#pragma unroll
        for (int j = 0; j < 4; ++j) {
            red[wv * NPB + lane + 64 * j] =
                make_float4(Ax[j].x + Ax[j].y, Ay[j].x + Ay[j].y,
                            Az[j].x + Az[j].y, Aw[j].x + Aw[j].y);
        }
        __syncthreads();
        {
            float4 r0 = red[tid];
            float4 r1 = red[NPB + tid];
            float4 r2 = red[2 * NPB + tid];
            float4 r3 = red[3 * NPB + tid];
            float ox = 0.5f * ((r0.x + r1.x) + (r2.x + r3.x));  // undo 2x fold
            float oy = 0.5f * ((r0.y + r1.y) + (r2.y + r3.y));
            float oz = 0.5f * ((r0.z + r1.z) + (r2.z + r3.z));
            float od = (r0.w + r1.w) + (r2.w + r3.w);
            float* dst = (float*)&acc[(size_t)it * TOT + b * NPTS + nbase + tid];
            atomicAdd(dst + 0, ox);
            atomicAdd(dst + 1, oy);
            atomicAdd(dst + 2, oz);
            atomicAdd(dst + 3, od);
        }
        // Sync only this (b,nt) group's MSPLIT blocks.
        group_barrier(ctr, (it + 1) * MSPLIT);
    }

    // Per-group pack: k==0 block writes its 256 outputs (acc[4] for this
    // n-range is complete after this group's 5th barrier).
    if (k == 0) {
        int n = nbase + tid;
        float4 a = acc[(size_t)4 * TOT + b * NPTS + n];
        float f = 1.0f / (s * a.w);                 // unscale + normalize
        float* ob = out + b * 3 * NPTS;
        ob[n]            = a.x * f;
        ob[NPTS + n]     = a.y * f;
        ob[2 * NPTS + n] = a.z * f;
    }
}

extern "C" void kernel_launch(void* const* d_in, const int* in_sizes, int n_in,
                              void* d_out, int out_size, void* d_ws, size_t ws_size,
                              hipStream_t stream) {
    const float* x = (const float*)d_in[0];
    float* out = (float*)d_out;
    float s = sqrtf(50.0f * LOG2E);                 // 8.4932...

    float4* acc = (float4*)d_ws;                    // 5 * TOT * 16 B = 1.47 MB
    int* bars = (int*)(acc + (size_t)5 * TOT);      // 72 padded counters

    // Zero acc buffers (atomic targets) and the group counters.
    hipMemsetAsync(acc, 0,
                   (size_t)5 * TOT * sizeof(float4) + NGRP * 16 * sizeof(int),
                   stream);

    ms_all<<<GRIDSZ, 256, 0, stream>>>(x, acc, bars, out, s);
}

// Round 11
// 232.669 us; speedup vs baseline: 1.3682x; 1.3682x over previous
//
#include <hip/hip_runtime.h>
#include <math.h>

// MeanShift: x (2,3,96,96) fp32, 5 iters of all-pairs Gaussian-weighted mean.
// R8 structure (best: 236us): 5x ms_iter dispatches + atomicAdd partial
// exchange + ms_pack. This round: hot loop unrolled to 8 m/iteration (two
// sequential 4-m sub-blocks; halves branch/addr overhead, doubles exp ILP),
// software prefetch dropped (R4-vs-R8 proved it neutral).
//
// Scaled space: s = sqrt(50*log2e) -> w = exp2(u), u = 2p.y - |p|^2 - |y|^2.
// LDS stages (2px,2py,2pz,-|p|^2); ypar stores PLAIN y (storing 2y was the
// rounds-5/6 NaN bug). exp stays hw v_exp_f32: packed-emulation (R7) and
// MFMA / pruning variants are ruled out by cycle arithmetic (see journal).

typedef float v2f __attribute__((ext_vector_type(2)));

#define NPTS   9216            // 96*96
#define NB     2
#define TOT    (NB * NPTS)     // 18432
#define MSPLIT 32              // m-slices per n-tile
#define SLICE  (NPTS / MSPLIT) // 288 m per block
#define WSLICE (SLICE / 4)     // 72 m per wave
#define NPB    256             // n per block (4 per thread)
#define NTILES (NPTS / NPB)    // 36
#define LOG2E  1.44269504088896340736f

__device__ __forceinline__ v2f splat2(float v) { return (v2f){v, v}; }

// acc[t][gid] = float4(num0,num1,num2,den), t=0..4, pre-zeroed, atomic-combined.

__global__ __launch_bounds__(256, 4) void ms_iter(const float* __restrict__ x,
                                                  const float4* __restrict__ accIn,
                                                  float4* __restrict__ accOut,
                                                  float s, int first) {
    __shared__ float4 smem[1024];               // 16 KB
    float* const xs = (float*)smem;             // [SLICE] 2*px
    float* const ys = xs + SLICE;               // 2*py
    float* const zs = ys + SLICE;               // 2*pz
    float* const ws = zs + SLICE;               // -|p|^2
    float4* const ypar = smem + SLICE;          // [NPB] (y0,y1,y2,-|y|^2)
    float4* const red  = smem;                  // [4][NPB] overlay (post-loop)

    const int tid  = threadIdx.x;
    const int lane = tid & 63;
    const int wv   = tid >> 6;
    const int k    = blockIdx.x % MSPLIT;
    const int tile = blockIdx.x / MSPLIT;
    const int b    = tile / NTILES;
    const int nt   = tile - b * NTILES;
    const int nbase = nt * NPB;
    const float* xb = x + b * 3 * NPTS;
    const int mbeg = k * SLICE;

    // SoA staging, scaled, 2x folded into coords.
    for (int i = tid; i < SLICE; i += 256) {
        int g = mbeg + i;
        float px = xb[g] * s;
        float py = xb[NPTS + g] * s;
        float pz = xb[2 * NPTS + g] * s;
        xs[i] = 2.f * px;
        ys[i] = 2.f * py;
        zs[i] = 2.f * pz;
        ws[i] = -fmaf(px, px, fmaf(py, py, pz * pz));
    }
    // y for this iteration (scaled space). PLAIN y (2x lives in LDS).
    {
        float y0, y1, y2;
        if (first) {
            int n = nbase + tid;
            y0 = xb[n] * s; y1 = xb[NPTS + n] * s; y2 = xb[2 * NPTS + n] * s;
        } else {
            float4 a = accIn[b * NPTS + nbase + tid];
            float inv = 1.0f / a.w;
            y0 = a.x * inv; y1 = a.y * inv; y2 = a.z * inv;
        }
        ypar[tid] = make_float4(y0, y1, y2,
                                -fmaf(y0, y0, fmaf(y1, y1, y2 * y2)));
    }
    __syncthreads();

    v2f Yx[4], Yy[4], Yz[4], Yw[4], Ax[4], Ay[4], Az[4], Aw[4];
#pragma unroll
    for (int j = 0; j < 4; ++j) {
        float4 yp = ypar[lane + 64 * j];
        Yx[j] = splat2(yp.x); Yy[j] = splat2(yp.y);
        Yz[j] = splat2(yp.z); Yw[j] = splat2(yp.w);
        Ax[j] = splat2(0.f); Ay[j] = splat2(0.f);
        Az[j] = splat2(0.f); Aw[j] = splat2(0.f);
    }

    const float* xsw = xs + wv * WSLICE;
    const float* ysw = ys + wv * WSLICE;
    const float* zsw = zs + wv * WSLICE;
    const float* wsw = ws + wv * WSLICE;

    // 8 m per loop iteration as two 4-m sub-blocks (9 iterations total).
    // Only 4 staging float4s live at a time -> VGPR stays low.
    for (int i = 0; i < WSLICE; i += 8) {
#pragma unroll
        for (int half = 0; half < 2; ++half) {
            const int o = i + 4 * half;
            float4 PX = *(const float4*)(xsw + o);
            float4 PY = *(const float4*)(ysw + o);
            float4 PZ = *(const float4*)(zsw + o);
            float4 PW = *(const float4*)(wsw + o);
            v2f px0 = (v2f){PX.x, PX.y}, px1 = (v2f){PX.z, PX.w};
            v2f py0 = (v2f){PY.x, PY.y}, py1 = (v2f){PY.z, PY.w};
            v2f pz0 = (v2f){PZ.x, PZ.y}, pz1 = (v2f){PZ.z, PZ.w};
            v2f pw0 = (v2f){PW.x, PW.y}, pw1 = (v2f){PW.z, PW.w};
#pragma unroll
            for (int j = 0; j < 4; ++j) {
                // u = 2p.y - |p|^2 - |y|^2 <= 0
                v2f t0 = pw0 + Yw[j];
                t0 = __builtin_elementwise_fma(pz0, Yz[j], t0);
                t0 = __builtin_elementwise_fma(py0, Yy[j], t0);
                t0 = __builtin_elementwise_fma(px0, Yx[j], t0);
                v2f t1 = pw1 + Yw[j];
                t1 = __builtin_elementwise_fma(pz1, Yz[j], t1);
                t1 = __builtin_elementwise_fma(py1, Yy[j], t1);
                t1 = __builtin_elementwise_fma(px1, Yx[j], t1);
                v2f w0, w1;
                w0.x = __builtin_amdgcn_exp2f(t0.x);
                w0.y = __builtin_amdgcn_exp2f(t0.y);
                w1.x = __builtin_amdgcn_exp2f(t1.x);
                w1.y = __builtin_amdgcn_exp2f(t1.y);
                Ax[j] = __builtin_elementwise_fma(w0, px0, Ax[j]);
                Ay[j] = __builtin_elementwise_fma(w0, py0, Ay[j]);
                Az[j] = __builtin_elementwise_fma(w0, pz0, Az[j]);
                Aw[j] += w0;
                Ax[j] = __builtin_elementwise_fma(w1, px1, Ax[j]);
                Ay[j] = __builtin_elementwise_fma(w1, py1, Ay[j]);
                Az[j] = __builtin_elementwise_fma(w1, pz1, Az[j]);
                Aw[j] += w1;
            }
        }
    }

    // Cross-wave reduction (red overlays staging; staging dead now).
    __syncthreads();
#pragma unroll
    for (int j = 0; j < 4; ++j) {
        red[wv * NPB + lane + 64 * j] =
            make_float4(Ax[j].x + Ax[j].y, Ay[j].x + Ay[j].y,
                        Az[j].x + Az[j].y, Aw[j].x + Aw[j].y);
    }
    __syncthreads();
    {
        float4 r0 = red[tid];
        float4 r1 = red[NPB + tid];
        float4 r2 = red[2 * NPB + tid];
        float4 r3 = red[3 * NPB + tid];
        // coords were accumulated with the 2x fold -> scale by 0.5
        float ox = 0.5f * ((r0.x + r1.x) + (r2.x + r3.x));
        float oy = 0.5f * ((r0.y + r1.y) + (r2.y + r3.y));
        float oz = 0.5f * ((r0.z + r1.z) + (r2.z + r3.z));
        float od = (r0.w + r1.w) + (r2.w + r3.w);
        float* dst = (float*)&accOut[b * NPTS + nbase + tid];
        atomicAdd(dst + 0, ox);
        atomicAdd(dst + 1, oy);
        atomicAdd(dst + 2, oz);
        atomicAdd(dst + 3, od);
    }
}

__global__ __launch_bounds__(256) void ms_pack(const float4* __restrict__ acc4,
                                               float* __restrict__ out,
                                               float invs) {
    int gid = blockIdx.x * 256 + threadIdx.x;
    int b = gid / NPTS;
    int n = gid - b * NPTS;
    float4 a = acc4[gid];
    float f = invs / a.w;                       // unscale + normalize
    float* ob = out + b * 3 * NPTS;
    ob[n]            = a.x * f;
    ob[NPTS + n]     = a.y * f;
    ob[2 * NPTS + n] = a.z * f;
}

extern "C" void kernel_launch(void* const* d_in, const int* in_sizes, int n_in,
                              void* d_out, int out_size, void* d_ws, size_t ws_size,
                              hipStream_t stream) {
    const float* x = (const float*)d_in[0];
    float* out = (float*)d_out;
    float s = sqrtf(50.0f * LOG2E);                 // 8.4932...

    float4* acc = (float4*)d_ws;                    // 5 * TOT * 16 B = 1.47 MB

    // Zero all 5 accumulator buffers (atomic targets) in one async memset.
    hipMemsetAsync(acc, 0, (size_t)5 * TOT * sizeof(float4), stream);

    for (int it = 0; it < 5; ++it) {
        const float4* accIn = (it == 0) ? nullptr : acc + (size_t)(it - 1) * TOT;
        ms_iter<<<NB * NTILES * MSPLIT, 256, 0, stream>>>(
            x, accIn, acc + (size_t)it * TOT, s, it == 0 ? 1 : 0);
    }
    ms_pack<<<TOT / 256, 256, 0, stream>>>(acc + (size_t)4 * TOT, out, 1.0f / s);
}